// Round 8
// baseline (103.263 us; speedup 1.0000x reference)
//
#include <hip/hip_runtime.h>
#include <math.h>

typedef unsigned short u16;
typedef unsigned long long u64;
typedef float    f32x4  __attribute__((ext_vector_type(4)));
typedef __bf16   bf16x8 __attribute__((ext_vector_type(8)));

#define NS    32768
#define KC    1024
#define INV_T 100.0f
#define TAU   2.0f

// ws layout (float offsets)
#define C2_OFF   0
#define SUMM_OFF 1024                      // [n][16 halfblocks] float4
#define SUMM_SZ  (NS * 16 * 4)
#define HIST_OFF (SUMM_OFF + SUMM_SZ)
#define PD_OFF   (HIST_OFF + KC)
#define PS_OFF   (PD_OFF + 8192)

// ct: tiled bf16 codebook, 16 tiles (64 codes) x 2048 chunks x 16B = 512 KB
// (lives in d_out, overwritten by refine's quantized output afterwards).
// chunk c within tile = ks*256 + sub*64 + row  (sub = k-octet, row = code 0..63)
#define TILE_U16 16384

__device__ __forceinline__ void gload_lds16(const void* g, void* l) {
    __builtin_amdgcn_global_load_lds((const __attribute__((address_space(1))) void*)g,
                                     (__attribute__((address_space(3))) void*)l, 16, 0, 0);
}

// --------------- cb prep: exact c2 + tiled bf16 codebook (64 blocks) ----
__global__ __launch_bounds__(256) void vq_cbprep(const float* __restrict__ cb,
                                                 u16* __restrict__ ct,
                                                 float* __restrict__ c2) {
    const int b = blockIdx.x;        // 64 blocks: tile T = b>>2, part p = b&3
    const int T = b >> 2, p = b & 3;
    const int t = threadIdx.x, w = t >> 6, lane = t & 63;

    // c2 for 16 rows (exact fp32)
    #pragma unroll
    for (int i = 0; i < 4; ++i) {
        int g = T * 64 + p * 16 + i * 4 + w;
        float4 v = reinterpret_cast<const float4*>(cb)[(size_t)g * 64 + lane];
        float s = v.x * v.x + v.y * v.y + v.z * v.z + v.w * v.w;
        #pragma unroll
        for (int off = 32; off; off >>= 1) s += __shfl_xor(s, off);
        if (lane == 0) c2[g] = s;
    }

    // tiled bf16: this block covers chunks [p*512, p*512+512) of tile T
    #pragma unroll
    for (int i = 0; i < 2; ++i) {
        int c = p * 512 + i * 256 + t;
        int ks = c >> 8, sub = (c >> 6) & 3, row = c & 63;
        const float* src = cb + (size_t)(T * 64 + row) * 256 + ks * 32 + sub * 8;
        float4 a0 = *reinterpret_cast<const float4*>(src);
        float4 a1 = *reinterpret_cast<const float4*>(src + 4);
        bf16x8 v;
        v[0]=(__bf16)a0.x; v[1]=(__bf16)a0.y; v[2]=(__bf16)a0.z; v[3]=(__bf16)a0.w;
        v[4]=(__bf16)a1.x; v[5]=(__bf16)a1.y; v[6]=(__bf16)a1.z; v[7]=(__bf16)a1.w;
        *reinterpret_cast<bf16x8*>(ct + (size_t)T * TILE_U16 + (size_t)c * 8) = v;
    }
}

// ---- distance MFMA: A persistent in registers, B dbuf-streamed via LDS.
//      512 threads (8 waves, 32 samples each = 256 samples) x 256 codes.
//      grid 512 = 128 sample-groups x 4 code-quarters; 2 blocks/CU, all resident.
__global__ __launch_bounds__(512, 4) void vq_dist(const float* __restrict__ x,
                                                  const u16* __restrict__ ct,
                                                  const float* __restrict__ c2,
                                                  float4* __restrict__ summ) {
    __shared__ __align__(16) u16 Bs[2][TILE_U16];   // 2 x 32 KB

    // XCD swizzle: each XCD owns 16 sample-groups x 4 code-quarters
    const int id = blockIdx.x;
    const int xcd = id & 7, r0 = id >> 3;          // r0 0..63
    const int sq = xcd * 16 + (r0 >> 2);           // 0..127
    const int cq = r0 & 3;                         // 0..3
    const int sBase = sq * 256;
    const int tile0 = cq * 4;

    const int t = threadIdx.x, w = t >> 6, lane = t & 63;   // w 0..7
    const int lo16 = lane & 15, hi = lane >> 4;

    #define STAGE(buf, tile)                                                      \
        do {                                                                      \
            const u16* bT_ = ct + (size_t)(tile) * TILE_U16;                      \
            _Pragma("unroll")                                                     \
            for (int i_ = 0; i_ < 4; ++i_) {                                      \
                int c0_ = w * 256 + i_ * 64;                                      \
                gload_lds16(bT_ + (size_t)(c0_ + lane) * 8, &Bs[buf][c0_ * 8]);   \
            }                                                                     \
        } while (0)

    STAGE(0, tile0);

    // Load this wave's entire A-operand (32 samples x 256 k) into 64 VGPRs.
    const float* aw = x + (size_t)(sBase + w * 32) * 256;
    bf16x8 af[2][8];
    #pragma unroll
    for (int m = 0; m < 2; ++m) {
        #pragma unroll
        for (int ks = 0; ks < 8; ++ks) {
            const float* ap = aw + (size_t)(m * 16 + lo16) * 256 + ks * 32 + hi * 8;
            float4 a0 = *reinterpret_cast<const float4*>(ap);
            float4 a1 = *reinterpret_cast<const float4*>(ap + 4);
            bf16x8 v;
            v[0]=(__bf16)a0.x; v[1]=(__bf16)a0.y; v[2]=(__bf16)a0.z; v[3]=(__bf16)a0.w;
            v[4]=(__bf16)a1.x; v[5]=(__bf16)a1.y; v[6]=(__bf16)a1.z; v[7]=(__bf16)a1.w;
            af[m][ks] = v;
        }
    }
    __syncthreads();

    int cur = 0;
    for (int tt = 0; tt < 4; ++tt) {
        if (tt < 3) STAGE(cur ^ 1, tile0 + tt + 1);   // overlaps with MFMAs below

        const u16* bsc = &Bs[cur][0];
        f32x4 acc[2][4];
        #pragma unroll
        for (int m = 0; m < 2; ++m)
            #pragma unroll
            for (int n = 0; n < 4; ++n) acc[m][n] = (f32x4)0.f;

        #pragma unroll
        for (int ks = 0; ks < 8; ++ks) {
            bf16x8 bfr[4];
            #pragma unroll
            for (int n = 0; n < 4; ++n)
                bfr[n] = *reinterpret_cast<const bf16x8*>(
                    &bsc[((size_t)ks * 256 + hi * 64 + n * 16 + lo16) * 8]);
            #pragma unroll
            for (int m = 0; m < 2; ++m)
                #pragma unroll
                for (int n = 0; n < 4; ++n)
                    acc[m][n] = __builtin_amdgcn_mfma_f32_16x16x32_bf16(af[m][ks], bfr[n], acc[m][n], 0, 0, 0);
        }

        // Epilogue for this 64-code tile: dd = c2 - 2*acc (x^2 cancels)
        const int cBase = (tile0 + tt) * 64;
        float c2v[4];
        #pragma unroll
        for (int j = 0; j < 4; ++j) c2v[j] = c2[cBase + j * 16 + lo16];

        #pragma unroll
        for (int m = 0; m < 2; ++m) {
            #pragma unroll
            for (int r = 0; r < 4; ++r) {
                const int R = sBase + w * 32 + m * 16 + hi * 4 + r;
                float dd[4];
                #pragma unroll
                for (int j = 0; j < 4; ++j) dd[j] = fmaf(-2.0f, acc[m][j][r], c2v[j]);
                float bm = fminf(fminf(dd[0], dd[1]), fminf(dd[2], dd[3]));
                #pragma unroll
                for (int off = 1; off < 16; off <<= 1) bm = fminf(bm, __shfl_xor(bm, off));
                const float thr = bm + TAU;
                u64 mk = 0ull;
                #pragma unroll
                for (int n = 0; n < 4; ++n) {
                    u64 b = __ballot(dd[n] < thr);
                    mk |= ((b >> (hi * 16)) & 0xFFFFull) << (n * 16);
                }
                if (lo16 == 0) {
                    float4 o;
                    o.x = bm;
                    o.y = 0.f;
                    o.z = __uint_as_float((unsigned)(mk & 0xFFFFFFFFull));
                    o.w = __uint_as_float((unsigned)(mk >> 32));
                    summ[(size_t)R * 16 + tile0 + tt] = o;
                }
            }
        }
        __syncthreads();     // stage(next) complete; buffer swap safe
        cur ^= 1;
    }
    #undef STAGE
}

// ---------- exact fp32 refine, 4-way ILP, fused gather + histogram ----
__global__ __launch_bounds__(256) void vq_refine(const float* __restrict__ x,
                                                 const float* __restrict__ cb,
                                                 const float* __restrict__ c2,
                                                 const float4* __restrict__ summ,
                                                 float* __restrict__ hist,
                                                 float* __restrict__ pd,
                                                 float* __restrict__ ps,
                                                 float* __restrict__ outq,
                                                 float* __restrict__ out_idx_f) {
    __shared__ int   cd_k[4][128];
    __shared__ float cd_d[4][128];
    __shared__ float rd[4], rs[4];

    const int wid = threadIdx.x >> 6, lane = threadIdx.x & 63;
    const int s = blockIdx.x * 4 + wid;
    const float4 xv = reinterpret_cast<const float4*>(x)[(size_t)s * 64 + lane];

    // exact ||x_s||^2 (all lanes)
    float x2s = xv.x * xv.x + xv.y * xv.y + xv.z * xv.z + xv.w * xv.w;
    #pragma unroll
    for (int off = 32; off; off >>= 1) x2s += __shfl_xor(x2s, off);

    // parallel min over the 16 half-block summaries
    float gm = summ[(size_t)s * 16 + (lane & 15)].x;
    #pragma unroll
    for (int off = 1; off < 16; off <<= 1) gm = fminf(gm, __shfl_xor(gm, off));
    const float lim = gm + TAU;

    const float4* cb4 = reinterpret_cast<const float4*>(cb);
    float m = 3.4e38f, S1 = 0.f, S2 = 0.f;
    int bk = 0, cnt = 0;

    for (int hb = 0; hb < 16; ++hb) {
        float4 sm = summ[(size_t)s * 16 + hb];
        if (sm.x > lim) continue;
        u64 mk = ((u64)__float_as_uint(sm.w) << 32) | __float_as_uint(sm.z);
        while (mk) {
            // grab up to 4 candidates (wave-uniform walk; ascending k)
            int vc = 1;
            int b0 = __ffsll(mk) - 1; mk &= mk - 1;
            int k0 = hb * 64 + b0, k1 = k0, k2 = k0, k3 = k0;
            if (mk) { int b = __ffsll(mk) - 1; mk &= mk - 1; k1 = hb * 64 + b; vc = 2; }
            if (mk) { int b = __ffsll(mk) - 1; mk &= mk - 1; k2 = hb * 64 + b; vc = 3; }
            if (mk) { int b = __ffsll(mk) - 1; mk &= mk - 1; k3 = hb * 64 + b; vc = 4; }

            float4 cv0 = cb4[(size_t)k0 * 64 + lane];
            float4 cv1 = cb4[(size_t)k1 * 64 + lane];
            float4 cv2 = cb4[(size_t)k2 * 64 + lane];
            float4 cv3 = cb4[(size_t)k3 * 64 + lane];
            float r0 = xv.x*cv0.x + xv.y*cv0.y + xv.z*cv0.z + xv.w*cv0.w;
            float r1 = xv.x*cv1.x + xv.y*cv1.y + xv.z*cv1.z + xv.w*cv1.w;
            float r2 = xv.x*cv2.x + xv.y*cv2.y + xv.z*cv2.z + xv.w*cv2.w;
            float r3 = xv.x*cv3.x + xv.y*cv3.y + xv.z*cv3.z + xv.w*cv3.w;
            #pragma unroll
            for (int off = 32; off; off >>= 1) {
                r0 += __shfl_xor(r0, off);
                r1 += __shfl_xor(r1, off);
                r2 += __shfl_xor(r2, off);
                r3 += __shfl_xor(r3, off);
            }
            float dk[4];
            dk[0] = (x2s - 2.0f * r0) + c2[k0];
            dk[1] = (x2s - 2.0f * r1) + c2[k1];
            dk[2] = (x2s - 2.0f * r2) + c2[k2];
            dk[3] = (x2s - 2.0f * r3) + c2[k3];
            int kk[4] = {k0, k1, k2, k3};

            #pragma unroll
            for (int j = 0; j < 4; ++j) {
                if (j >= vc) break;
                float d = dk[j];
                if (lane == 0 && cnt < 128) { cd_k[wid][cnt] = kk[j]; cd_d[wid][cnt] = d; }
                ++cnt;
                if (S1 == 0.f)   { m = d; S1 = 1.f; S2 = 0.f; bk = kk[j]; }
                else if (d < m)  { float f = __expf((d - m) * INV_T);
                                   S2 = f * (S2 + (m - d) * S1);
                                   S1 = S1 * f + 1.f; m = d; bk = kk[j]; }
                else             { float e = __expf((m - d) * INV_T);
                                   S1 += e; S2 += e * (d - m); }
            }
        }
    }
    float sent = S2 * INV_T / S1 + logf(S1);
    if (lane == 0) { rd[wid] = m; rs[wid] = sent; }
    __syncthreads();

    // lane-parallel histogram update
    if (cnt > 128) cnt = 128;
    for (int c = lane; c < cnt; c += 64) {
        float dkv = cd_d[wid][c]; int k = cd_k[wid][c];
        atomicAdd(&hist[k], __expf((m - dkv) * INV_T) / S1);
    }

    // fused gather: quantized row = codebook[bk]
    reinterpret_cast<float4*>(outq)[(size_t)s * 64 + lane] = cb4[(size_t)bk * 64 + lane];
    if (lane == 0) out_idx_f[s] = (float)bk;

    if (threadIdx.x == 0) {
        pd[blockIdx.x] = rd[0] + rd[1] + rd[2] + rd[3];
        ps[blockIdx.x] = rs[0] + rs[1] + rs[2] + rs[3];
    }
}

// -------------------------------------------------------------- finalize ----
__global__ __launch_bounds__(256) void vq_finalize(const float* __restrict__ hist,
                                                   const float* __restrict__ pd,
                                                   const float* __restrict__ ps,
                                                   float* __restrict__ loss_out) {
    float ae = 0.f, sd = 0.f, se = 0.f;
    for (int k = threadIdx.x; k < KC; k += 256) {
        float p = hist[k] * (1.0f / (float)NS);
        ae += -p * logf(p + 1e-5f);
    }
    for (int b = threadIdx.x; b < 8192; b += 256) { sd += pd[b]; se += ps[b]; }
    #pragma unroll
    for (int off = 32; off; off >>= 1) {
        ae += __shfl_xor(ae, off); sd += __shfl_xor(sd, off); se += __shfl_xor(se, off);
    }
    __shared__ float r[3][4];
    int wid = threadIdx.x >> 6, lane = threadIdx.x & 63;
    if (lane == 0) { r[0][wid] = ae; r[1][wid] = sd; r[2][wid] = se; }
    __syncthreads();
    if (threadIdx.x == 0) {
        float AE = r[0][0] + r[0][1] + r[0][2] + r[0][3];
        float SD = r[1][0] + r[1][1] + r[1][2] + r[1][3];
        float SE = r[2][0] + r[2][1] + r[2][2] + r[2][3];
        float latent = 1.25f * SD / 8388608.0f;
        loss_out[0] = latent + 0.1f * (SE * (1.0f / (float)NS) - AE);
    }
}

extern "C" void kernel_launch(void* const* d_in, const int* in_sizes, int n_in,
                              void* d_out, int out_size, void* d_ws, size_t ws_size,
                              hipStream_t stream) {
    const float* x  = (const float*)d_in[0];
    const float* cb = (const float*)d_in[1];
    float* out = (float*)d_out;
    float* ws  = (float*)d_ws;

    // tiled bf16 codebook in first 512 KB of d_out (overwritten by refine later)
    u16* ct = (u16*)d_out;

    hipMemsetAsync(ws + HIST_OFF, 0, KC * sizeof(float), stream);

    vq_cbprep<<<64, 256, 0, stream>>>(cb, ct, ws + C2_OFF);
    vq_dist<<<512, 512, 0, stream>>>(x, ct, ws + C2_OFF, (float4*)(ws + SUMM_OFF));
    vq_refine<<<NS / 4, 256, 0, stream>>>(x, cb, ws + C2_OFF,
                                          (const float4*)(ws + SUMM_OFF),
                                          ws + HIST_OFF, ws + PD_OFF, ws + PS_OFF,
                                          out, out + 8388609);
    vq_finalize<<<1, 256, 0, stream>>>(ws + HIST_OFF, ws + PD_OFF, ws + PS_OFF,
                                       out + 8388608);
}